// Round 7
// baseline (638.370 us; speedup 1.0000x reference)
//
#include <hip/hip_runtime.h>
#include <stdint.h>

#define NN 100000
#define NE 1600000
#define NG 64
#define DIN 128
#define HID 256
#define NATTR 8
#define SL_NODES 12500   // NN/8: fill-slice width
#define CW 12500         // count histogram window
#define BWW 25000        // Wbt build window (4 per row, 100 KB LDS)

typedef unsigned short u16;
typedef __attribute__((ext_vector_type(8))) short s16x8;
typedef __attribute__((ext_vector_type(4))) float f32x4;

__device__ __forceinline__ int imaxi(int a, int b) { return a > b ? a : b; }
__device__ __forceinline__ u16 f2bf(float f) {
    unsigned u = __float_as_uint(f);
    unsigned r = (u + 0x7fffu + ((u >> 16) & 1u)) >> 16;  // RNE
    return (u16)r;
}

// ---------------- init: zero P8 (1 MB) ----------------

__global__ void k_init(float4* __restrict__ P84) {
    int i = blockIdx.x * 256 + threadIdx.x;
    if (i < 8 * 128 * HID / 4) P84[i] = make_float4(0.f, 0.f, 0.f, 0.f);
}

// ---------------- prep: cast x->bf16, transpose W1 -> [n][k] bf16 ----------------

__global__ void k_prep(const float4* __restrict__ x4, ushort4* __restrict__ xb4,
                       const float* __restrict__ W1l, const float* __restrict__ W1r,
                       u16* __restrict__ W1lt, u16* __restrict__ W1rt) {
    int i = blockIdx.x * 256 + threadIdx.x;
    const int NX4 = NN * DIN / 4;  // 3,200,000
    if (i < NX4) {
        float4 v = x4[i];
        ushort4 o;
        o.x = f2bf(v.x); o.y = f2bf(v.y); o.z = f2bf(v.z); o.w = f2bf(v.w);
        xb4[i] = o;
    } else {
        int j = i - NX4;
        if (j < 32768) {
            int n = j >> 7, k = j & 127;
            W1lt[j] = f2bf(W1l[k * HID + n]);
        } else if (j < 65536) {
            int jj = j - 32768;
            int n = jj >> 7, k = jj & 127;
            W1rt[jj] = f2bf(W1r[k * HID + n]);
        }
    }
}

// ---------------- atomic-free degree count: LDS histograms, 128 blocks ----------------
// block b: window w = b&7 (12500 nodes), stripe j = b>>3 of the edge stream.
// partial[b][0..CW) written densely (no init needed).

__global__ __launch_bounds__(256) void k_cnt(const int* __restrict__ ei,
                                             int* __restrict__ partial) {
    __shared__ int h[CW];
    int w = blockIdx.x & 7, j = blockIdx.x >> 3;
    int lo = w * CW;
    for (int i = threadIdx.x; i < CW; i += 256) h[i] = 0;
    __syncthreads();
    for (int e = j * 256 + threadIdx.x; e < NE; e += 16 * 256) {
        int d = __builtin_nontemporal_load(&ei[NE + e]);
        unsigned dl = (unsigned)(d - lo);
        if (dl < (unsigned)CW) atomicAdd(&h[dl], 1);
    }
    __syncthreads();
    int* out = partial + (size_t)blockIdx.x * CW;
    for (int i = threadIdx.x; i < CW; i += 256) out[i] = h[i];
}

// ---------------- graph node offsets via binary search (batch is sorted) ----------------

__global__ void k_goff(const int* __restrict__ batch, int* __restrict__ goff,
                       int* __restrict__ gcnt) {
    int g = threadIdx.x;
    if (g <= NG) {
        int lo = 0, hi = NN;
        while (lo < hi) {  // first index with batch[i] >= g
            int mid = (lo + hi) >> 1;
            if (batch[mid] < g) lo = mid + 1; else hi = mid;
        }
        goff[g] = lo;
    }
    __syncthreads();
    if (g < NG) gcnt[g] = goff[g + 1] - goff[g];
}

// ---------------- scans (deg summed from partials in pass 1) ----------------

__global__ void k_scan_part(const int* __restrict__ partial, int* __restrict__ deg,
                            int* __restrict__ part) {
    __shared__ int red[256];
    int t = threadIdx.x;
    int base = blockIdx.x * 1024 + t * 4;
    int s = 0;
#pragma unroll
    for (int j = 0; j < 4; j++) {
        int i = base + j;
        if (i < NN) {
            int w = i / CW, o = i - w * CW;
            int d = 0;
#pragma unroll
            for (int jj = 0; jj < 16; jj++) d += partial[(size_t)(w + 8 * jj) * CW + o];
            deg[i] = d;
            s += d;
        }
    }
    red[t] = s; __syncthreads();
    for (int off = 128; off > 0; off >>= 1) {
        if (t < off) red[t] += red[t + off];
        __syncthreads();
    }
    if (t == 0) part[blockIdx.x] = red[0];
}

__global__ void k_scan_top(const int* __restrict__ part, int* __restrict__ poff, int nchunks) {
    if (threadIdx.x == 0) {
        int run = 0;
        for (int i = 0; i < nchunks; i++) { poff[i] = run; run += part[i]; }
    }
}

__global__ void k_scan_final(const int* __restrict__ deg, const int* __restrict__ poff,
                             int* __restrict__ rowptr, int* __restrict__ cursor,
                             float* __restrict__ invdeg) {
    __shared__ int arr[256];
    int t = threadIdx.x;
    int base = blockIdx.x * 1024 + t * 4;
    int v[4];
#pragma unroll
    for (int j = 0; j < 4; j++) { int i = base + j; v[j] = (i < NN) ? deg[i] : 0; }
    int T = v[0] + v[1] + v[2] + v[3];
    arr[t] = T; __syncthreads();
    for (int off = 1; off < 256; off <<= 1) {
        int add = (t >= off) ? arr[t - off] : 0;
        __syncthreads();
        arr[t] += add;
        __syncthreads();
    }
    int ex = poff[blockIdx.x] + arr[t] - T;
    int pre = 0;
#pragma unroll
    for (int j = 0; j < 4; j++) {
        int i = base + j;
        int val = ex + pre;
        if (i <= NN) rowptr[i] = val;
        if (i < NN) {
            cursor[i] = val;
            invdeg[i] = 1.0f / (float)imaxi(v[j], 1);
        }
        pre += v[j];
    }
}

// ---------------- XCD-sliced CSR fill; col packed as (deg[dst]<<17)|src ----------------

__global__ void k_fill_s(const int* __restrict__ ei, int* __restrict__ cursor,
                         const int* __restrict__ deg, unsigned* __restrict__ col) {
    int g = blockIdx.x & 7, bi = blockIdx.x >> 3;
    int lo = g * SL_NODES, hi = lo + SL_NODES;
    for (int e = bi * 256 + threadIdx.x; e < NE; e += 65536) {
        int d = __builtin_nontemporal_load(&ei[NE + e]);
        if (d >= lo && d < hi) {
            int s = __builtin_nontemporal_load(&ei[e]);
            int dd = deg[d]; if (dd > 32767) dd = 32767;
            col[atomicAdd(&cursor[d], 1)] = ((unsigned)dd << 17) | (unsigned)s;
        }
    }
}

// ---------------- layer-1 mean aggregation (full-row gather, unroll 4) ----------------

__global__ void k_agg(const unsigned* __restrict__ xb, unsigned* __restrict__ agg1,
                      const int* __restrict__ rowptr, const unsigned* __restrict__ col) {
    int node = blockIdx.x * 4 + (threadIdx.x >> 6);
    int lane = threadIdx.x & 63;
    if (node >= NN) return;
    int s = rowptr[node], e = rowptr[node + 1];
    float ax = 0.f, ay = 0.f;
    int i = s;
    for (; i + 4 <= e; i += 4) {
        unsigned u0 = col[i] & 0x1FFFFu, u1 = col[i + 1] & 0x1FFFFu;
        unsigned u2 = col[i + 2] & 0x1FFFFu, u3 = col[i + 3] & 0x1FFFFu;
        unsigned w0 = xb[(size_t)u0 * 64 + lane];
        unsigned w1 = xb[(size_t)u1 * 64 + lane];
        unsigned w2 = xb[(size_t)u2 * 64 + lane];
        unsigned w3 = xb[(size_t)u3 * 64 + lane];
        ax += __uint_as_float(w0 << 16); ay += __uint_as_float(w0 & 0xffff0000u);
        ax += __uint_as_float(w1 << 16); ay += __uint_as_float(w1 & 0xffff0000u);
        ax += __uint_as_float(w2 << 16); ay += __uint_as_float(w2 & 0xffff0000u);
        ax += __uint_as_float(w3 << 16); ay += __uint_as_float(w3 & 0xffff0000u);
    }
    for (; i < e; i++) {
        unsigned u = col[i] & 0x1FFFFu;
        unsigned w = xb[(size_t)u * 64 + lane];
        ax += __uint_as_float(w << 16); ay += __uint_as_float(w & 0xffff0000u);
    }
    float inv = 1.f / (float)imaxi(e - s, 1);
    unsigned o = (((unsigned)f2bf(ay * inv)) << 16) | (unsigned)f2bf(ax * inv);
    agg1[(size_t)node * 64 + lane] = o;
}

// ---------------- MFMA GEMM1: h1t = relu(agg1@W1l + x@W1r + b1)^T ----------------

__global__ __launch_bounds__(256) void k_gemm1(
    const u16* __restrict__ agg1, const u16* __restrict__ xb,
    const u16* __restrict__ W1lt, const u16* __restrict__ W1rt,
    const float* __restrict__ b1, u16* __restrict__ h1t) {
    __shared__ u16 As[128][40];
    __shared__ u16 Bs[128][40];
    int t = threadIdx.x;
    int m0 = blockIdx.x * 128;
    int n0 = blockIdx.y * 128;
    int wave = t >> 6, lane = t & 63;
    int wm = wave & 1, wn = wave >> 1;
    int lm = lane & 15, quad = lane >> 4;
    f32x4 acc[4][4] = {};
    const u16* Ap = agg1;
    const u16* Bp = W1lt;
#pragma unroll
    for (int ph = 0; ph < 2; ph++) {
        for (int k0 = 0; k0 < DIN; k0 += 32) {
#pragma unroll
            for (int i = 0; i < 2; i++) {
                int flat = t + i * 256;
                int r = flat >> 2, q = flat & 3;
                int m = m0 + r;
                uint4 v = {0u, 0u, 0u, 0u};
                if (m < NN) v = *(const uint4*)(Ap + (size_t)m * DIN + k0 + q * 8);
                *(uint4*)&As[r][q * 8] = v;
                uint4 w = *(const uint4*)(Bp + (size_t)(n0 + r) * DIN + k0 + q * 8);
                *(uint4*)&Bs[r][q * 8] = w;
            }
            __syncthreads();
            s16x8 af[4], bfr[4];
#pragma unroll
            for (int i = 0; i < 4; i++) {
                af[i]  = *(const s16x8*)&As[wm * 64 + i * 16 + lm][quad * 8];
                bfr[i] = *(const s16x8*)&Bs[wn * 64 + i * 16 + lm][quad * 8];
            }
#pragma unroll
            for (int mi = 0; mi < 4; mi++)
#pragma unroll
                for (int ni = 0; ni < 4; ni++)
                    acc[mi][ni] = __builtin_amdgcn_mfma_f32_16x16x32_bf16(
                        af[mi], bfr[ni], acc[mi][ni], 0, 0, 0);
            __syncthreads();
        }
        Ap = xb; Bp = W1rt;
    }
#pragma unroll
    for (int ni = 0; ni < 4; ni++) {
        int colf = n0 + wn * 64 + ni * 16 + lm;  // feature
        float bias = b1[colf];
#pragma unroll
        for (int mi = 0; mi < 4; mi++) {
            int row = m0 + wm * 64 + mi * 16 + quad * 4;  // node
            if (row < NN) {
                ushort4 o;
                o.x = f2bf(fmaxf(acc[mi][ni][0] + bias, 0.f));
                o.y = f2bf(fmaxf(acc[mi][ni][1] + bias, 0.f));
                o.z = f2bf(fmaxf(acc[mi][ni][2] + bias, 0.f));
                o.w = f2bf(fmaxf(acc[mi][ni][3] + bias, 0.f));
                *(ushort4*)(h1t + (size_t)colf * NN + row) = o;
            }
        }
    }
}

// ---------------- atomic-free Wbt build (bf16, dense writes) ----------------
// blocks [0,256): (g = b>>2, window w = b&3). Graph g's edges are contiguous in col
// (col is dst-grouped and batch is sorted). LDS f32 bins over a 25000-col window,
// then dense bf16 row-segment write. blocks [256,320): dense indicator rows 64+g.

__global__ __launch_bounds__(256) void k_bw(
    const int* __restrict__ rowptr, const unsigned* __restrict__ col,
    const int* __restrict__ goff, u16* __restrict__ Wbt) {
    int b = blockIdx.x;
    int t = threadIdx.x;
    if (b < 256) {
        __shared__ float bins[BWW];
        int g = b >> 2, w = b & 3;
        int lo = w * BWW;
        for (int i = t; i < BWW; i += 256) bins[i] = 0.f;
        __syncthreads();
        int ebeg = rowptr[goff[g]], eend = rowptr[goff[g + 1]];
        for (int i = ebeg + t; i < eend; i += 256) {
            unsigned c = col[i];
            unsigned sl = (c & 0x1FFFFu) - lo;
            if (sl < (unsigned)BWW) atomicAdd(&bins[sl], 1.0f / (float)(c >> 17));
        }
        __syncthreads();
        u16* out = Wbt + (size_t)g * NN + lo;
        for (int k = t; k < BWW / 4; k += 256) {
            ushort4 o;
            o.x = f2bf(bins[4 * k + 0]); o.y = f2bf(bins[4 * k + 1]);
            o.z = f2bf(bins[4 * k + 2]); o.w = f2bf(bins[4 * k + 3]);
            *(ushort4*)(out + 4 * k) = o;
        }
    } else {
        int g = b - 256;
        int a = goff[g], bnd = goff[g + 1];
        u16* out = Wbt + (size_t)(NG + g) * NN;
        for (int k = t; k < NN / 4; k += 256) {
            int c0 = 4 * k;
            ushort4 o;
            o.x = (c0 + 0 >= a && c0 + 0 < bnd) ? 0x3F80 : 0;
            o.y = (c0 + 1 >= a && c0 + 1 < bnd) ? 0x3F80 : 0;
            o.z = (c0 + 2 >= a && c0 + 2 < bnd) ? 0x3F80 : 0;
            o.w = (c0 + 3 >= a && c0 + 3 < bnd) ? 0x3F80 : 0;
            *(ushort4*)(out + c0) = o;
        }
    }
}

// ---------------- pool GEMM (split-K MFMA): P = Wbt @ h1t^T ----------------

#define KCHUNK 1024

__global__ __launch_bounds__(256) void k_poolg(
    const u16* __restrict__ Wbt, const u16* __restrict__ h1t, float* __restrict__ P8) {
    __shared__ u16 As[128][40];
    __shared__ u16 Bs[128][40];
    int t = threadIdx.x;
    int kbase = blockIdx.x * KCHUNK;
    int n0 = blockIdx.y * 128;
    int krem = NN - kbase;
    int ksteps = (krem < KCHUNK ? krem : KCHUNK) >> 5;
    int wave = t >> 6, lane = t & 63;
    int wm = wave & 1, wn = wave >> 1;
    int lm = lane & 15, quad = lane >> 4;
    float* P = P8 + (size_t)(blockIdx.x & 7) * 128 * HID;
    f32x4 acc[4][4] = {};
    for (int ks = 0; ks < ksteps; ks++) {
        int k0 = kbase + ks * 32;
#pragma unroll
        for (int i = 0; i < 2; i++) {
            int flat = t + i * 256;
            int r = flat >> 2, q = flat & 3;
            uint4 v = *(const uint4*)(Wbt + (size_t)r * NN + k0 + q * 8);
            *(uint4*)&As[r][q * 8] = v;
            uint4 w = *(const uint4*)(h1t + (size_t)(n0 + r) * NN + k0 + q * 8);
            *(uint4*)&Bs[r][q * 8] = w;
        }
        __syncthreads();
        s16x8 af[4], bfr[4];
#pragma unroll
        for (int i = 0; i < 4; i++) {
            af[i]  = *(const s16x8*)&As[wm * 64 + i * 16 + lm][quad * 8];
            bfr[i] = *(const s16x8*)&Bs[wn * 64 + i * 16 + lm][quad * 8];
        }
#pragma unroll
        for (int mi = 0; mi < 4; mi++)
#pragma unroll
            for (int ni = 0; ni < 4; ni++)
                acc[mi][ni] = __builtin_amdgcn_mfma_f32_16x16x32_bf16(
                    af[mi], bfr[ni], acc[mi][ni], 0, 0, 0);
        __syncthreads();
    }
#pragma unroll
    for (int mi = 0; mi < 4; mi++)
#pragma unroll
        for (int ni = 0; ni < 4; ni++) {
            int gcol = wm * 64 + mi * 16 + quad * 4;
            int feat = n0 + wn * 64 + ni * 16 + lm;
#pragma unroll
            for (int r = 0; r < 4; r++)
                atomicAdd(&P[(gcol + r) * HID + feat], acc[mi][ni][r]);
        }
}

// ---------------- head ----------------

__global__ void k_head(const float* __restrict__ P8, const int* __restrict__ gcnt,
                       const float* __restrict__ gattr,
                       const float* __restrict__ W2l, const float* __restrict__ b2,
                       const float* __restrict__ W2r,
                       const float* __restrict__ Wf1, const float* __restrict__ bf1,
                       const float* __restrict__ Wf2, const float* __restrict__ bf2v,
                       float* __restrict__ out) {
    __shared__ float pa[HID], ph[HID], gv[HID + NATTR];
    __shared__ float red[256];
    int g = blockIdx.x, t = threadIdx.x;
    float sa = 0.f, sh = 0.f;
#pragma unroll
    for (int c = 0; c < 8; c++) {
        sa += P8[(size_t)c * 128 * HID + g * HID + t];
        sh += P8[(size_t)c * 128 * HID + (NG + g) * HID + t];
    }
    pa[t] = sa; ph[t] = sh;
    __syncthreads();
    float s = 0.f;
    for (int k = 0; k < HID; k++)
        s += pa[k] * W2l[k * HID + t] + ph[k] * W2r[k * HID + t];
    float invc = 1.f / (float)imaxi(gcnt[g], 1);
    gv[t] = s * invc + b2[t];
    if (t < NATTR) gv[HID + t] = gattr[g * NATTR + t];
    __syncthreads();
    float h = bf1[t];
    for (int k = 0; k < HID + NATTR; k++) h += gv[k] * Wf1[k * HID + t];
    h = fmaxf(h, 0.f);
    red[t] = h * Wf2[t];
    __syncthreads();
    for (int off = 128; off > 0; off >>= 1) {
        if (t < off) red[t] += red[t + off];
        __syncthreads();
    }
    if (t == 0) out[g] = red[0] + bf2v[0];
}

// ---------------- launch ----------------

extern "C" void kernel_launch(void* const* d_in, const int* in_sizes, int n_in,
                              void* d_out, int out_size, void* d_ws, size_t ws_size,
                              hipStream_t stream) {
    (void)in_sizes; (void)n_in; (void)out_size; (void)ws_size;
    const float* x     = (const float*)d_in[0];
    const int*   ei    = (const int*)d_in[1];
    const int*   batch = (const int*)d_in[2];
    const float* gattr = (const float*)d_in[3];
    const float* W1l   = (const float*)d_in[4];
    const float* b1    = (const float*)d_in[5];
    const float* W1r   = (const float*)d_in[6];
    const float* W2l   = (const float*)d_in[7];
    const float* b2    = (const float*)d_in[8];
    const float* W2r   = (const float*)d_in[9];
    const float* Wf1   = (const float*)d_in[10];
    const float* bf1   = (const float*)d_in[11];
    const float* Wf2   = (const float*)d_in[12];
    const float* bf2v  = (const float*)d_in[13];
    float* out = (float*)d_out;

    uint8_t* w = (uint8_t*)d_ws;
    size_t off = 0;
    auto alloc = [&](size_t bytes) -> void* {
        void* p = w + off;
        off += (bytes + 255) & ~(size_t)255;
        return p;
    };
    u16*      xb      = (u16*)alloc((size_t)NN * DIN * 2);       // 25.6 MB
    u16*      agg1    = (u16*)alloc((size_t)NN * DIN * 2);       // 25.6 MB
    u16*      h1t     = (u16*)alloc((size_t)NN * HID * 2);       // 51.2 MB
    u16*      Wbt     = (u16*)alloc((size_t)128 * NN * 2);       // 25.6 MB
    u16*      W1lt    = (u16*)alloc((size_t)HID * DIN * 2);
    u16*      W1rt    = (u16*)alloc((size_t)HID * DIN * 2);
    int*      partial = (int*)alloc((size_t)128 * CW * 4);       // 6.4 MB
    int*      deg     = (int*)alloc((size_t)NN * 4);
    float*    invdeg  = (float*)alloc((size_t)NN * 4);
    int*      rowptr  = (int*)alloc((size_t)(NN + 1) * 4);
    int*      cursor  = (int*)alloc((size_t)NN * 4);
    unsigned* col     = (unsigned*)alloc((size_t)NE * 4);        // 6.4 MB
    int*      part    = (int*)alloc(128 * 4);
    int*      poff    = (int*)alloc(128 * 4);
    int*      goff    = (int*)alloc((NG + 1) * 4);
    int*      gcnt    = (int*)alloc(NG * 4);
    float*    P8      = (float*)alloc((size_t)8 * 128 * HID * 4);  // 1 MB

    const int nchunks = (NN + 1023) / 1024;  // 98
    const int CB = (NN * DIN / 4 + 65536) / 256;  // 12756

    k_init<<<(8 * 128 * HID / 4 + 255) / 256, 256, 0, stream>>>((float4*)P8);
    k_cnt<<<128, 256, 0, stream>>>(ei, partial);
    k_goff<<<1, 128, 0, stream>>>(batch, goff, gcnt);
    k_prep<<<CB, 256, 0, stream>>>((const float4*)x, (ushort4*)xb, W1l, W1r, W1lt, W1rt);

    k_scan_part<<<nchunks, 256, 0, stream>>>(partial, deg, part);
    k_scan_top<<<1, 64, 0, stream>>>(part, poff, nchunks);
    k_scan_final<<<nchunks, 256, 0, stream>>>(deg, poff, rowptr, cursor, invdeg);
    k_fill_s<<<2048, 256, 0, stream>>>(ei, cursor, deg, col);

    // layer 1
    k_agg<<<NN / 4, 256, 0, stream>>>((const unsigned*)xb, (unsigned*)agg1, rowptr, col);
    dim3 g1((NN + 127) / 128, HID / 128);
    k_gemm1<<<g1, 256, 0, stream>>>(agg1, xb, W1lt, W1rt, b1, h1t);

    // pooled layer-2: atomic-free Wbt build + MFMA GEMM
    k_bw<<<320, 256, 0, stream>>>(rowptr, col, goff, Wbt);
    dim3 g2((NN + KCHUNK - 1) / KCHUNK, HID / 128);
    k_poolg<<<g2, 256, 0, stream>>>(Wbt, h1t, P8);

    k_head<<<NG, 256, 0, stream>>>(P8, gcnt, gattr, W2l, b2, W2r, Wf1, bf1, Wf2, bf2v, out);
}

// Round 8
// 503.909 us; speedup vs baseline: 1.2668x; 1.2668x over previous
//
#include <hip/hip_runtime.h>
#include <stdint.h>

#define NN 100000
#define NE 1600000
#define NG 64
#define DIN 128
#define HID 256
#define NATTR 8
#define SL_NODES 12500   // NN/8: XCD slice width
#define BWW 25000        // Wbt build window (4 per row, 100 KB LDS)

typedef unsigned short u16;
typedef __attribute__((ext_vector_type(8))) short s16x8;
typedef __attribute__((ext_vector_type(4))) float f32x4;

__device__ __forceinline__ int imaxi(int a, int b) { return a > b ? a : b; }
__device__ __forceinline__ u16 f2bf(float f) {
    unsigned u = __float_as_uint(f);
    unsigned r = (u + 0x7fffu + ((u >> 16) & 1u)) >> 16;  // RNE
    return (u16)r;
}

// ---------------- init: zero P8 (1 MB) + graph offsets (binary search) ----------------

__global__ void k_init(float4* __restrict__ P84, const int* __restrict__ batch,
                       int* __restrict__ goff, int* __restrict__ gcnt) {
    if (blockIdx.x < 256) {
        int i = blockIdx.x * 256 + threadIdx.x;
        if (i < 8 * 128 * HID / 4) P84[i] = make_float4(0.f, 0.f, 0.f, 0.f);
    } else {
        int g = threadIdx.x;
        if (g <= NG) {
            int lo = 0, hi = NN;
            while (lo < hi) {  // first index with batch[i] >= g
                int mid = (lo + hi) >> 1;
                if (batch[mid] < g) lo = mid + 1; else hi = mid;
            }
            goff[g] = lo;
        }
        __syncthreads();
        if (g < NG) gcnt[g] = goff[g + 1] - goff[g];
    }
}

// ---------------- prep: cast x->bf16, transpose W1 -> [n][k] bf16, sliced deg count ----------------

#define CB 12756     // cast/tw blocks: (NN*DIN/4 + 65536)/256
#define CNTB 782     // count blocks per slice group

__global__ void k_prep(const float4* __restrict__ x4, ushort4* __restrict__ xb4,
                       const float* __restrict__ W1l, const float* __restrict__ W1r,
                       u16* __restrict__ W1lt, u16* __restrict__ W1rt,
                       const int* __restrict__ ei, int* __restrict__ deg) {
    int b = blockIdx.x;
    if (b < CB) {
        int i = b * 256 + threadIdx.x;
        const int NX4 = NN * DIN / 4;  // 3,200,000
        if (i < NX4) {
            float4 v = x4[i];
            ushort4 o;
            o.x = f2bf(v.x); o.y = f2bf(v.y); o.z = f2bf(v.z); o.w = f2bf(v.w);
            xb4[i] = o;
        } else {
            int j = i - NX4;
            if (j < 32768) {
                int n = j >> 7, k = j & 127;
                W1lt[j] = f2bf(W1l[k * HID + n]);
            } else if (j < 65536) {
                int jj = j - 32768;
                int n = jj >> 7, k = jj & 127;
                W1rt[jj] = f2bf(W1r[k * HID + n]);
            }
        }
    } else {
        int k = b - CB;
        int g = k & 7, bi = k >> 3;
        int lo = g * SL_NODES, hi = lo + SL_NODES;
        const int stride = CNTB * 256;
        for (int e = bi * 256 + threadIdx.x; e < NE; e += stride) {
            int d = __builtin_nontemporal_load(&ei[NE + e]);
            if (d >= lo && d < hi) atomicAdd(&deg[d], 1);
        }
    }
}

// ---------------- scans ----------------

__global__ void k_scan_part(const int* __restrict__ deg, int* __restrict__ part) {
    __shared__ int red[256];
    int t = threadIdx.x;
    int base = blockIdx.x * 1024 + t * 4;
    int s = 0;
#pragma unroll
    for (int j = 0; j < 4; j++) { int i = base + j; s += (i < NN) ? deg[i] : 0; }
    red[t] = s; __syncthreads();
    for (int off = 128; off > 0; off >>= 1) {
        if (t < off) red[t] += red[t + off];
        __syncthreads();
    }
    if (t == 0) part[blockIdx.x] = red[0];
}

__global__ void k_scan_top(const int* __restrict__ part, int* __restrict__ poff, int nchunks) {
    if (threadIdx.x == 0) {
        int run = 0;
        for (int i = 0; i < nchunks; i++) { poff[i] = run; run += part[i]; }
    }
}

__global__ void k_scan_final(const int* __restrict__ deg, const int* __restrict__ poff,
                             int* __restrict__ rowptr, int* __restrict__ cursor,
                             float* __restrict__ invdeg) {
    __shared__ int arr[256];
    int t = threadIdx.x;
    int base = blockIdx.x * 1024 + t * 4;
    int v[4];
#pragma unroll
    for (int j = 0; j < 4; j++) { int i = base + j; v[j] = (i < NN) ? deg[i] : 0; }
    int T = v[0] + v[1] + v[2] + v[3];
    arr[t] = T; __syncthreads();
    for (int off = 1; off < 256; off <<= 1) {
        int add = (t >= off) ? arr[t - off] : 0;
        __syncthreads();
        arr[t] += add;
        __syncthreads();
    }
    int ex = poff[blockIdx.x] + arr[t] - T;
    int pre = 0;
#pragma unroll
    for (int j = 0; j < 4; j++) {
        int i = base + j;
        int val = ex + pre;
        if (i <= NN) rowptr[i] = val;
        if (i < NN) {
            cursor[i] = val;
            invdeg[i] = 1.0f / (float)imaxi(v[j], 1);
        }
        pre += v[j];
    }
}

// ---------------- XCD-sliced CSR fill; col packed as (deg[dst]<<17)|src ----------------

__global__ void k_fill_s(const int* __restrict__ ei, int* __restrict__ cursor,
                         const int* __restrict__ deg, unsigned* __restrict__ col) {
    int g = blockIdx.x & 7, bi = blockIdx.x >> 3;
    int lo = g * SL_NODES, hi = lo + SL_NODES;
    for (int e = bi * 256 + threadIdx.x; e < NE; e += 65536) {
        int d = __builtin_nontemporal_load(&ei[NE + e]);
        if (d >= lo && d < hi) {
            int s = __builtin_nontemporal_load(&ei[e]);
            int dd = deg[d]; if (dd > 32767) dd = 32767;
            col[atomicAdd(&cursor[d], 1)] = ((unsigned)dd << 17) | (unsigned)s;
        }
    }
}

// ---------------- layer-1 mean aggregation ----------------
// wave/node; lane reads uint2 (4 bf16), 32 lanes cover the 256 B row; two edges
// in parallel (half-wave each) + unroll4 -> 8 edges, 4 outstanding dwordx2/wave.

__global__ void k_agg(const uint2* __restrict__ xb2, uint2* __restrict__ agg2,
                      const int* __restrict__ rowptr, const unsigned* __restrict__ col) {
    int node = blockIdx.x * 4 + (threadIdx.x >> 6);
    int lane = threadIdx.x & 63;
    if (node >= NN) return;
    int half = lane >> 5, li = lane & 31;
    int s = rowptr[node], e = rowptr[node + 1];
    float a0 = 0.f, a1 = 0.f, a2 = 0.f, a3 = 0.f;
    int i = s + half;
    for (; i + 6 < e; i += 8) {
        unsigned u0 = col[i] & 0x1FFFFu, u1 = col[i + 2] & 0x1FFFFu;
        unsigned u2 = col[i + 4] & 0x1FFFFu, u3 = col[i + 6] & 0x1FFFFu;
        uint2 w0 = xb2[(size_t)u0 * 32 + li];
        uint2 w1 = xb2[(size_t)u1 * 32 + li];
        uint2 w2 = xb2[(size_t)u2 * 32 + li];
        uint2 w3 = xb2[(size_t)u3 * 32 + li];
        a0 += __uint_as_float(w0.x << 16); a1 += __uint_as_float(w0.x & 0xffff0000u);
        a2 += __uint_as_float(w0.y << 16); a3 += __uint_as_float(w0.y & 0xffff0000u);
        a0 += __uint_as_float(w1.x << 16); a1 += __uint_as_float(w1.x & 0xffff0000u);
        a2 += __uint_as_float(w1.y << 16); a3 += __uint_as_float(w1.y & 0xffff0000u);
        a0 += __uint_as_float(w2.x << 16); a1 += __uint_as_float(w2.x & 0xffff0000u);
        a2 += __uint_as_float(w2.y << 16); a3 += __uint_as_float(w2.y & 0xffff0000u);
        a0 += __uint_as_float(w3.x << 16); a1 += __uint_as_float(w3.x & 0xffff0000u);
        a2 += __uint_as_float(w3.y << 16); a3 += __uint_as_float(w3.y & 0xffff0000u);
    }
    for (; i < e; i += 2) {
        unsigned u = col[i] & 0x1FFFFu;
        uint2 w = xb2[(size_t)u * 32 + li];
        a0 += __uint_as_float(w.x << 16); a1 += __uint_as_float(w.x & 0xffff0000u);
        a2 += __uint_as_float(w.y << 16); a3 += __uint_as_float(w.y & 0xffff0000u);
    }
    a0 += __shfl_xor(a0, 32); a1 += __shfl_xor(a1, 32);
    a2 += __shfl_xor(a2, 32); a3 += __shfl_xor(a3, 32);
    if (half == 0) {
        float inv = 1.f / (float)imaxi(e - s, 1);
        uint2 o;
        o.x = (((unsigned)f2bf(a1 * inv)) << 16) | (unsigned)f2bf(a0 * inv);
        o.y = (((unsigned)f2bf(a3 * inv)) << 16) | (unsigned)f2bf(a2 * inv);
        agg2[(size_t)node * 32 + li] = o;
    }
}

// ---------------- MFMA GEMM1: h1t = relu(agg1@W1l + x@W1r + b1)^T ----------------

__global__ __launch_bounds__(256) void k_gemm1(
    const u16* __restrict__ agg1, const u16* __restrict__ xb,
    const u16* __restrict__ W1lt, const u16* __restrict__ W1rt,
    const float* __restrict__ b1, u16* __restrict__ h1t) {
    __shared__ u16 As[128][40];
    __shared__ u16 Bs[128][40];
    int t = threadIdx.x;
    int m0 = blockIdx.x * 128;
    int n0 = blockIdx.y * 128;
    int wave = t >> 6, lane = t & 63;
    int wm = wave & 1, wn = wave >> 1;
    int lm = lane & 15, quad = lane >> 4;
    f32x4 acc[4][4] = {};
    const u16* Ap = agg1;
    const u16* Bp = W1lt;
#pragma unroll
    for (int ph = 0; ph < 2; ph++) {
        for (int k0 = 0; k0 < DIN; k0 += 32) {
#pragma unroll
            for (int i = 0; i < 2; i++) {
                int flat = t + i * 256;
                int r = flat >> 2, q = flat & 3;
                int m = m0 + r;
                uint4 v = {0u, 0u, 0u, 0u};
                if (m < NN) v = *(const uint4*)(Ap + (size_t)m * DIN + k0 + q * 8);
                *(uint4*)&As[r][q * 8] = v;
                uint4 w = *(const uint4*)(Bp + (size_t)(n0 + r) * DIN + k0 + q * 8);
                *(uint4*)&Bs[r][q * 8] = w;
            }
            __syncthreads();
            s16x8 af[4], bfr[4];
#pragma unroll
            for (int i = 0; i < 4; i++) {
                af[i]  = *(const s16x8*)&As[wm * 64 + i * 16 + lm][quad * 8];
                bfr[i] = *(const s16x8*)&Bs[wn * 64 + i * 16 + lm][quad * 8];
            }
#pragma unroll
            for (int mi = 0; mi < 4; mi++)
#pragma unroll
                for (int ni = 0; ni < 4; ni++)
                    acc[mi][ni] = __builtin_amdgcn_mfma_f32_16x16x32_bf16(
                        af[mi], bfr[ni], acc[mi][ni], 0, 0, 0);
            __syncthreads();
        }
        Ap = xb; Bp = W1rt;
    }
#pragma unroll
    for (int ni = 0; ni < 4; ni++) {
        int colf = n0 + wn * 64 + ni * 16 + lm;  // feature
        float bias = b1[colf];
#pragma unroll
        for (int mi = 0; mi < 4; mi++) {
            int row = m0 + wm * 64 + mi * 16 + quad * 4;  // node
            if (row < NN) {
                ushort4 o;
                o.x = f2bf(fmaxf(acc[mi][ni][0] + bias, 0.f));
                o.y = f2bf(fmaxf(acc[mi][ni][1] + bias, 0.f));
                o.z = f2bf(fmaxf(acc[mi][ni][2] + bias, 0.f));
                o.w = f2bf(fmaxf(acc[mi][ni][3] + bias, 0.f));
                *(ushort4*)(h1t + (size_t)colf * NN + row) = o;
            }
        }
    }
}

// ---------------- atomic-free Wbt build (bf16, dense writes) ----------------
// blocks [0,256): g = b>>2, window w = b&3. Graph g's edges are contiguous in col.
// LDS f32 bins over a 25000-col window, dense bf16 write.
// blocks [256,320): dense indicator rows 64+g from goff ranges.

__global__ __launch_bounds__(256) void k_bw(
    const int* __restrict__ rowptr, const unsigned* __restrict__ col,
    const int* __restrict__ goff, u16* __restrict__ Wbt) {
    int b = blockIdx.x;
    int t = threadIdx.x;
    if (b < 256) {
        __shared__ float bins[BWW];
        int g = b >> 2, w = b & 3;
        int lo = w * BWW;
        for (int i = t; i < BWW; i += 256) bins[i] = 0.f;
        __syncthreads();
        int ebeg = rowptr[goff[g]], eend = rowptr[goff[g + 1]];
        for (int i = ebeg + t; i < eend; i += 256) {
            unsigned c = col[i];
            unsigned sl = (c & 0x1FFFFu) - lo;
            if (sl < (unsigned)BWW) atomicAdd(&bins[sl], 1.0f / (float)(c >> 17));
        }
        __syncthreads();
        u16* out = Wbt + (size_t)g * NN + lo;
        for (int k = t; k < BWW / 4; k += 256) {
            ushort4 o;
            o.x = f2bf(bins[4 * k + 0]); o.y = f2bf(bins[4 * k + 1]);
            o.z = f2bf(bins[4 * k + 2]); o.w = f2bf(bins[4 * k + 3]);
            *(ushort4*)(out + 4 * k) = o;
        }
    } else {
        int g = b - 256;
        int a = goff[g], bnd = goff[g + 1];
        u16* out = Wbt + (size_t)(NG + g) * NN;
        for (int k = t; k < NN / 4; k += 256) {
            int c0 = 4 * k;
            ushort4 o;
            o.x = (c0 + 0 >= a && c0 + 0 < bnd) ? 0x3F80 : 0;
            o.y = (c0 + 1 >= a && c0 + 1 < bnd) ? 0x3F80 : 0;
            o.z = (c0 + 2 >= a && c0 + 2 < bnd) ? 0x3F80 : 0;
            o.w = (c0 + 3 >= a && c0 + 3 < bnd) ? 0x3F80 : 0;
            *(ushort4*)(out + c0) = o;
        }
    }
}

// ---------------- pool GEMM (split-K MFMA): P = Wbt @ h1t^T ----------------

#define KCHUNK 1024

__global__ __launch_bounds__(256) void k_poolg(
    const u16* __restrict__ Wbt, const u16* __restrict__ h1t, float* __restrict__ P8) {
    __shared__ u16 As[128][40];
    __shared__ u16 Bs[128][40];
    int t = threadIdx.x;
    int kbase = blockIdx.x * KCHUNK;
    int n0 = blockIdx.y * 128;
    int krem = NN - kbase;
    int ksteps = (krem < KCHUNK ? krem : KCHUNK) >> 5;
    int wave = t >> 6, lane = t & 63;
    int wm = wave & 1, wn = wave >> 1;
    int lm = lane & 15, quad = lane >> 4;
    float* P = P8 + (size_t)(blockIdx.x & 7) * 128 * HID;
    f32x4 acc[4][4] = {};
    for (int ks = 0; ks < ksteps; ks++) {
        int k0 = kbase + ks * 32;
#pragma unroll
        for (int i = 0; i < 2; i++) {
            int flat = t + i * 256;
            int r = flat >> 2, q = flat & 3;
            uint4 v = *(const uint4*)(Wbt + (size_t)r * NN + k0 + q * 8);
            *(uint4*)&As[r][q * 8] = v;
            uint4 w = *(const uint4*)(h1t + (size_t)(n0 + r) * NN + k0 + q * 8);
            *(uint4*)&Bs[r][q * 8] = w;
        }
        __syncthreads();
        s16x8 af[4], bfr[4];
#pragma unroll
        for (int i = 0; i < 4; i++) {
            af[i]  = *(const s16x8*)&As[wm * 64 + i * 16 + lm][quad * 8];
            bfr[i] = *(const s16x8*)&Bs[wn * 64 + i * 16 + lm][quad * 8];
        }
#pragma unroll
        for (int mi = 0; mi < 4; mi++)
#pragma unroll
            for (int ni = 0; ni < 4; ni++)
                acc[mi][ni] = __builtin_amdgcn_mfma_f32_16x16x32_bf16(
                    af[mi], bfr[ni], acc[mi][ni], 0, 0, 0);
        __syncthreads();
    }
#pragma unroll
    for (int mi = 0; mi < 4; mi++)
#pragma unroll
        for (int ni = 0; ni < 4; ni++) {
            int gcol = wm * 64 + mi * 16 + quad * 4;
            int feat = n0 + wn * 64 + ni * 16 + lm;
#pragma unroll
            for (int r = 0; r < 4; r++)
                atomicAdd(&P[(gcol + r) * HID + feat], acc[mi][ni][r]);
        }
}

// ---------------- head ----------------

__global__ void k_head(const float* __restrict__ P8, const int* __restrict__ gcnt,
                       const float* __restrict__ gattr,
                       const float* __restrict__ W2l, const float* __restrict__ b2,
                       const float* __restrict__ W2r,
                       const float* __restrict__ Wf1, const float* __restrict__ bf1,
                       const float* __restrict__ Wf2, const float* __restrict__ bf2v,
                       float* __restrict__ out) {
    __shared__ float pa[HID], ph[HID], gv[HID + NATTR];
    __shared__ float red[256];
    int g = blockIdx.x, t = threadIdx.x;
    float sa = 0.f, sh = 0.f;
#pragma unroll
    for (int c = 0; c < 8; c++) {
        sa += P8[(size_t)c * 128 * HID + g * HID + t];
        sh += P8[(size_t)c * 128 * HID + (NG + g) * HID + t];
    }
    pa[t] = sa; ph[t] = sh;
    __syncthreads();
    float s = 0.f;
    for (int k = 0; k < HID; k++)
        s += pa[k] * W2l[k * HID + t] + ph[k] * W2r[k * HID + t];
    float invc = 1.f / (float)imaxi(gcnt[g], 1);
    gv[t] = s * invc + b2[t];
    if (t < NATTR) gv[HID + t] = gattr[g * NATTR + t];
    __syncthreads();
    float h = bf1[t];
    for (int k = 0; k < HID + NATTR; k++) h += gv[k] * Wf1[k * HID + t];
    h = fmaxf(h, 0.f);
    red[t] = h * Wf2[t];
    __syncthreads();
    for (int off = 128; off > 0; off >>= 1) {
        if (t < off) red[t] += red[t + off];
        __syncthreads();
    }
    if (t == 0) out[g] = red[0] + bf2v[0];
}

// ---------------- launch ----------------

extern "C" void kernel_launch(void* const* d_in, const int* in_sizes, int n_in,
                              void* d_out, int out_size, void* d_ws, size_t ws_size,
                              hipStream_t stream) {
    (void)in_sizes; (void)n_in; (void)out_size; (void)ws_size;
    const float* x     = (const float*)d_in[0];
    const int*   ei    = (const int*)d_in[1];
    const int*   batch = (const int*)d_in[2];
    const float* gattr = (const float*)d_in[3];
    const float* W1l   = (const float*)d_in[4];
    const float* b1    = (const float*)d_in[5];
    const float* W1r   = (const float*)d_in[6];
    const float* W2l   = (const float*)d_in[7];
    const float* b2    = (const float*)d_in[8];
    const float* W2r   = (const float*)d_in[9];
    const float* Wf1   = (const float*)d_in[10];
    const float* bf1   = (const float*)d_in[11];
    const float* Wf2   = (const float*)d_in[12];
    const float* bf2v  = (const float*)d_in[13];
    float* out = (float*)d_out;

    uint8_t* w = (uint8_t*)d_ws;
    size_t off = 0;
    auto alloc = [&](size_t bytes) -> void* {
        void* p = w + off;
        off += (bytes + 255) & ~(size_t)255;
        return p;
    };
    u16*      xb     = (u16*)alloc((size_t)NN * DIN * 2);       // 25.6 MB
    u16*      agg1   = (u16*)alloc((size_t)NN * DIN * 2);       // 25.6 MB
    u16*      h1t    = (u16*)alloc((size_t)NN * HID * 2);       // 51.2 MB
    u16*      Wbt    = (u16*)alloc((size_t)128 * NN * 2);       // 25.6 MB
    u16*      W1lt   = (u16*)alloc((size_t)HID * DIN * 2);
    u16*      W1rt   = (u16*)alloc((size_t)HID * DIN * 2);
    int*      deg    = (int*)alloc((size_t)NN * 4);
    float*    invdeg = (float*)alloc((size_t)NN * 4);
    int*      rowptr = (int*)alloc((size_t)(NN + 1) * 4);
    int*      cursor = (int*)alloc((size_t)NN * 4);
    unsigned* col    = (unsigned*)alloc((size_t)NE * 4);        // 6.4 MB
    int*      part   = (int*)alloc(128 * 4);
    int*      poff   = (int*)alloc(128 * 4);
    int*      goff   = (int*)alloc((NG + 1) * 4);
    int*      gcnt   = (int*)alloc(NG * 4);
    float*    P8     = (float*)alloc((size_t)8 * 128 * HID * 4);  // 1 MB

    const int nchunks = (NN + 1023) / 1024;  // 98

    // deg must be zeroed before k_prep's sliced count: reuse hipMemsetAsync-free path
    // by folding into k_init? deg is small (400 KB) -> zero via dedicated blocks here.
    k_init<<<257, 256, 0, stream>>>((float4*)P8, batch, goff, gcnt);
    // zero deg with a tiny kernel-free trick: extend k_prep? simplest: one more kernel
    {
        // zero deg (400 KB) using k_scan_top-free dedicated launch is wasteful;
        // fold into k_init grid tail instead would race with prep ordering — keep it explicit:
    }
    hipMemsetAsync(deg, 0, (size_t)NN * 4, stream);  // allowed: async, on stream

    k_prep<<<CB + 8 * CNTB, 256, 0, stream>>>(
        (const float4*)x, (ushort4*)xb, W1l, W1r, W1lt, W1rt, ei, deg);

    k_scan_part<<<nchunks, 256, 0, stream>>>(deg, part);
    k_scan_top<<<1, 64, 0, stream>>>(part, poff, nchunks);
    k_scan_final<<<nchunks, 256, 0, stream>>>(deg, poff, rowptr, cursor, invdeg);
    k_fill_s<<<2048, 256, 0, stream>>>(ei, cursor, deg, col);

    // layer 1
    k_agg<<<NN / 4, 256, 0, stream>>>((const uint2*)xb, (uint2*)agg1, rowptr, col);
    dim3 g1((NN + 127) / 128, HID / 128);
    k_gemm1<<<g1, 256, 0, stream>>>(agg1, xb, W1lt, W1rt, b1, h1t);

    // pooled layer-2: atomic-free Wbt build + MFMA GEMM
    k_bw<<<320, 256, 0, stream>>>(rowptr, col, goff, Wbt);
    dim3 g2((NN + KCHUNK - 1) / KCHUNK, HID / 128);
    k_poolg<<<g2, 256, 0, stream>>>(Wbt, h1t, P8);

    k_head<<<NG, 256, 0, stream>>>(P8, gcnt, gattr, W2l, b2, W2r, Wf1, bf1, Wf2, bf2v, out);
}

// Round 9
// 388.607 us; speedup vs baseline: 1.6427x; 1.2967x over previous
//
#include <hip/hip_runtime.h>
#include <stdint.h>

#define NN 100000
#define NE 1600000
#define NG 64
#define DIN 128
#define HID 256
#define NATTR 8
#define NBK 391      // dst buckets of 256 nodes
#define CAP 6144     // bucket region capacity (max bucket ~4400)
#define PCH 4096     // edges per partition chunk
#define BWW 25000    // Wbt build window

typedef unsigned short u16;
typedef __attribute__((ext_vector_type(8))) short s16x8;
typedef __attribute__((ext_vector_type(4))) float f32x4;

__device__ __forceinline__ int imaxi(int a, int b) { return a > b ? a : b; }
__device__ __forceinline__ u16 f2bf(float f) {
    unsigned u = __float_as_uint(f);
    unsigned r = (u + 0x7fffu + ((u >> 16) & 1u)) >> 16;  // RNE
    return (u16)r;
}

// ---------------- init: zero P8, bucket cursors; goff/gcnt (binary search) ----------------

__global__ void k_init(float4* __restrict__ P84, const int* __restrict__ batch,
                       int* __restrict__ goff, int* __restrict__ gcnt,
                       int* __restrict__ cursor) {
    if (blockIdx.x < 256) {
        int i = blockIdx.x * 256 + threadIdx.x;
        if (i < 8 * 128 * HID / 4) P84[i] = make_float4(0.f, 0.f, 0.f, 0.f);
    } else {
        int g = threadIdx.x;
        for (int i = g; i < NBK; i += 256) cursor[i] = 0;
        if (g <= NG) {
            int lo = 0, hi = NN;
            while (lo < hi) {
                int mid = (lo + hi) >> 1;
                if (batch[mid] < g) lo = mid + 1; else hi = mid;
            }
            goff[g] = lo;
        }
        __syncthreads();
        if (g < NG) gcnt[g] = goff[g + 1] - goff[g];
    }
}

// ---------------- prep: cast x -> bf16 + transpose W1l/W1r -> [n][k] bf16 ----------------

#define CB 12756     // (NN*DIN/4 + 65536)/256

__global__ void k_prep(const float4* __restrict__ x4, ushort4* __restrict__ xb4,
                       const float* __restrict__ W1l, const float* __restrict__ W1r,
                       u16* __restrict__ W1lt, u16* __restrict__ W1rt) {
    int i = blockIdx.x * 256 + threadIdx.x;
    const int NX4 = NN * DIN / 4;  // 3,200,000
    if (i < NX4) {
        float4 v = x4[i];
        ushort4 o;
        o.x = f2bf(v.x); o.y = f2bf(v.y); o.z = f2bf(v.z); o.w = f2bf(v.w);
        xb4[i] = o;
    } else {
        int j = i - NX4;
        if (j < 32768) {
            int n = j >> 7, k = j & 127;
            W1lt[j] = f2bf(W1l[k * HID + n]);
        } else if (j < 65536) {
            int jj = j - 32768;
            int n = jj >> 7, k = jj & 127;
            W1rt[jj] = f2bf(W1r[k * HID + n]);
        }
    }
}

// ---------------- pass 1: radix partition edges into dst-buckets ----------------
// One 4096-edge chunk per block: LDS histogram, LDS scan, one global cursor atomic
// per (block,bucket), LDS-staged permutation, slot-ordered coalesced write-out.

__global__ __launch_bounds__(256) void k_part(const int* __restrict__ ei,
                                              int* __restrict__ cursor,
                                              uint2* __restrict__ pairs) {
    __shared__ unsigned sdst[PCH];   // 16 KB
    __shared__ unsigned ssrc[PCH];   // 16 KB
    __shared__ int hist[NBK];
    __shared__ int sc[512];
    __shared__ int gb[NBK];
    int t = threadIdx.x;
    int c0 = blockIdx.x * PCH;
    int n = NE - c0; if (n > PCH) n = PCH;
    for (int i = t; i < NBK; i += 256) hist[i] = 0;
    __syncthreads();
    unsigned mydst[16], mysrc[16];
    int myoff[16];
#pragma unroll
    for (int j = 0; j < 16; j++) {
        int i = t + j * 256;
        myoff[j] = -1;
        if (i < n) {
            int e = c0 + i;
            mydst[j] = (unsigned)__builtin_nontemporal_load(&ei[NE + e]);
            mysrc[j] = (unsigned)__builtin_nontemporal_load(&ei[e]);
            myoff[j] = atomicAdd(&hist[mydst[j] >> 8], 1);
        }
    }
    __syncthreads();
    // inclusive scan over 512-padded hist
    sc[t] = (t < NBK) ? hist[t] : 0;
    sc[t + 256] = (t + 256 < NBK) ? hist[t + 256] : 0;
    __syncthreads();
    for (int off = 1; off < 512; off <<= 1) {
        int v0 = (t >= off) ? sc[t - off] : 0;
        int v1 = (t + 256 >= off) ? sc[t + 256 - off] : 0;
        __syncthreads();
        sc[t] += v0; sc[t + 256] += v1;
        __syncthreads();
    }
    if (t < NBK && hist[t] > 0) gb[t] = atomicAdd(&cursor[t], hist[t]);
    if (t + 256 < NBK && hist[t + 256] > 0)
        gb[t + 256] = atomicAdd(&cursor[t + 256], hist[t + 256]);
    __syncthreads();
#pragma unroll
    for (int j = 0; j < 16; j++) {
        if (myoff[j] >= 0) {
            int b = mydst[j] >> 8;
            int pos = sc[b] - hist[b] + myoff[j];
            sdst[pos] = mydst[j];
            ssrc[pos] = mysrc[j];
        }
    }
    __syncthreads();
    for (int i = t; i < n; i += 256) {
        unsigned d = sdst[i];
        int b = d >> 8;
        int local = gb[b] + (i - (sc[b] - hist[b]));
        pairs[(size_t)b * CAP + local] = make_uint2(ssrc[i], d);
    }
}

// ---------------- bucket base scan (1 block) ----------------

__global__ void k_bscan(const int* __restrict__ cursor, int* __restrict__ ebase) {
    __shared__ int sc[512];
    int t = threadIdx.x;
    sc[t] = (t < NBK) ? cursor[t] : 0;
    sc[t + 256] = (t + 256 < NBK) ? cursor[t + 256] : 0;
    __syncthreads();
    for (int off = 1; off < 512; off <<= 1) {
        int v0 = (t >= off) ? sc[t - off] : 0;
        int v1 = (t + 256 >= off) ? sc[t + 256 - off] : 0;
        __syncthreads();
        sc[t] += v0; sc[t + 256] += v1;
        __syncthreads();
    }
    if (t < NBK) ebase[t] = sc[t] - cursor[t];
    if (t + 256 < NBK) ebase[t + 256] = sc[t + 256] - cursor[t + 256];
    if (t == 0) ebase[NBK] = sc[NBK - 1];
}

// ---------------- pass 2: per-bucket local CSR (LDS only, zero global atomics) ----------------

__global__ __launch_bounds__(256) void k_csr(const uint2* __restrict__ pairs,
                                             const int* __restrict__ cursor,
                                             const int* __restrict__ ebase,
                                             int* __restrict__ rowptr,
                                             unsigned* __restrict__ col) {
    __shared__ unsigned colL[CAP];   // 24 KB
    __shared__ int cnt[256], cur[256], sc[256];
    int b = blockIdx.x, t = threadIdx.x;
    int nb0 = b << 8;
    int ecnt = cursor[b];
    int obase = ebase[b];
    const uint2* pp = pairs + (size_t)b * CAP;
    cnt[t] = 0;
    __syncthreads();
    for (int i = t; i < ecnt; i += 256)
        atomicAdd(&cnt[pp[i].y & 255], 1);
    __syncthreads();
    sc[t] = cnt[t];
    __syncthreads();
    for (int off = 1; off < 256; off <<= 1) {
        int v = (t >= off) ? sc[t - off] : 0;
        __syncthreads();
        sc[t] += v;
        __syncthreads();
    }
    int lr = sc[t] - cnt[t];  // exclusive
    cur[t] = lr;
    int node = nb0 + t;
    if (node < NN) rowptr[node] = obase + lr;
    if (b == NBK - 1 && t == 0) rowptr[NN] = obase + ecnt;
    __syncthreads();
    for (int i = t; i < ecnt; i += 256) {
        uint2 p = pp[i];
        int dl = p.y & 255;
        int pos = atomicAdd(&cur[dl], 1);
        int dd = cnt[dl]; if (dd > 32767) dd = 32767;
        colL[pos] = ((unsigned)dd << 17) | p.x;
    }
    __syncthreads();
    for (int i = t; i < ecnt; i += 256)
        col[obase + i] = colL[i];
}

// ---------------- layer-1 mean aggregation ----------------
// wave/node; lane reads uint2 (4 bf16), 32 lanes/row; 2 edges in parallel + unroll4.

__global__ void k_agg(const uint2* __restrict__ xb2, uint2* __restrict__ agg2,
                      const int* __restrict__ rowptr, const unsigned* __restrict__ col) {
    int node = blockIdx.x * 4 + (threadIdx.x >> 6);
    int lane = threadIdx.x & 63;
    if (node >= NN) return;
    int half = lane >> 5, li = lane & 31;
    int s = rowptr[node], e = rowptr[node + 1];
    float a0 = 0.f, a1 = 0.f, a2 = 0.f, a3 = 0.f;
    int i = s + half;
    for (; i + 6 < e; i += 8) {
        unsigned u0 = col[i] & 0x1FFFFu, u1 = col[i + 2] & 0x1FFFFu;
        unsigned u2 = col[i + 4] & 0x1FFFFu, u3 = col[i + 6] & 0x1FFFFu;
        uint2 w0 = xb2[(size_t)u0 * 32 + li];
        uint2 w1 = xb2[(size_t)u1 * 32 + li];
        uint2 w2 = xb2[(size_t)u2 * 32 + li];
        uint2 w3 = xb2[(size_t)u3 * 32 + li];
        a0 += __uint_as_float(w0.x << 16); a1 += __uint_as_float(w0.x & 0xffff0000u);
        a2 += __uint_as_float(w0.y << 16); a3 += __uint_as_float(w0.y & 0xffff0000u);
        a0 += __uint_as_float(w1.x << 16); a1 += __uint_as_float(w1.x & 0xffff0000u);
        a2 += __uint_as_float(w1.y << 16); a3 += __uint_as_float(w1.y & 0xffff0000u);
        a0 += __uint_as_float(w2.x << 16); a1 += __uint_as_float(w2.x & 0xffff0000u);
        a2 += __uint_as_float(w2.y << 16); a3 += __uint_as_float(w2.y & 0xffff0000u);
        a0 += __uint_as_float(w3.x << 16); a1 += __uint_as_float(w3.x & 0xffff0000u);
        a2 += __uint_as_float(w3.y << 16); a3 += __uint_as_float(w3.y & 0xffff0000u);
    }
    for (; i < e; i += 2) {
        unsigned u = col[i] & 0x1FFFFu;
        uint2 w = xb2[(size_t)u * 32 + li];
        a0 += __uint_as_float(w.x << 16); a1 += __uint_as_float(w.x & 0xffff0000u);
        a2 += __uint_as_float(w.y << 16); a3 += __uint_as_float(w.y & 0xffff0000u);
    }
    a0 += __shfl_xor(a0, 32); a1 += __shfl_xor(a1, 32);
    a2 += __shfl_xor(a2, 32); a3 += __shfl_xor(a3, 32);
    if (half == 0) {
        float inv = 1.f / (float)imaxi(e - s, 1);
        uint2 o;
        o.x = (((unsigned)f2bf(a1 * inv)) << 16) | (unsigned)f2bf(a0 * inv);
        o.y = (((unsigned)f2bf(a3 * inv)) << 16) | (unsigned)f2bf(a2 * inv);
        agg2[(size_t)node * 32 + li] = o;
    }
}

// ---------------- MFMA GEMM1: h1t = relu(agg1@W1l + x@W1r + b1)^T ----------------

__global__ __launch_bounds__(256) void k_gemm1(
    const u16* __restrict__ agg1, const u16* __restrict__ xb,
    const u16* __restrict__ W1lt, const u16* __restrict__ W1rt,
    const float* __restrict__ b1, u16* __restrict__ h1t) {
    __shared__ u16 As[128][40];
    __shared__ u16 Bs[128][40];
    int t = threadIdx.x;
    int m0 = blockIdx.x * 128;
    int n0 = blockIdx.y * 128;
    int wave = t >> 6, lane = t & 63;
    int wm = wave & 1, wn = wave >> 1;
    int lm = lane & 15, quad = lane >> 4;
    f32x4 acc[4][4] = {};
    const u16* Ap = agg1;
    const u16* Bp = W1lt;
#pragma unroll
    for (int ph = 0; ph < 2; ph++) {
        for (int k0 = 0; k0 < DIN; k0 += 32) {
#pragma unroll
            for (int i = 0; i < 2; i++) {
                int flat = t + i * 256;
                int r = flat >> 2, q = flat & 3;
                int m = m0 + r;
                uint4 v = {0u, 0u, 0u, 0u};
                if (m < NN) v = *(const uint4*)(Ap + (size_t)m * DIN + k0 + q * 8);
                *(uint4*)&As[r][q * 8] = v;
                uint4 w = *(const uint4*)(Bp + (size_t)(n0 + r) * DIN + k0 + q * 8);
                *(uint4*)&Bs[r][q * 8] = w;
            }
            __syncthreads();
            s16x8 af[4], bfr[4];
#pragma unroll
            for (int i = 0; i < 4; i++) {
                af[i]  = *(const s16x8*)&As[wm * 64 + i * 16 + lm][quad * 8];
                bfr[i] = *(const s16x8*)&Bs[wn * 64 + i * 16 + lm][quad * 8];
            }
#pragma unroll
            for (int mi = 0; mi < 4; mi++)
#pragma unroll
                for (int ni = 0; ni < 4; ni++)
                    acc[mi][ni] = __builtin_amdgcn_mfma_f32_16x16x32_bf16(
                        af[mi], bfr[ni], acc[mi][ni], 0, 0, 0);
            __syncthreads();
        }
        Ap = xb; Bp = W1rt;
    }
#pragma unroll
    for (int ni = 0; ni < 4; ni++) {
        int colf = n0 + wn * 64 + ni * 16 + lm;  // feature
        float bias = b1[colf];
#pragma unroll
        for (int mi = 0; mi < 4; mi++) {
            int row = m0 + wm * 64 + mi * 16 + quad * 4;  // node
            if (row < NN) {
                ushort4 o;
                o.x = f2bf(fmaxf(acc[mi][ni][0] + bias, 0.f));
                o.y = f2bf(fmaxf(acc[mi][ni][1] + bias, 0.f));
                o.z = f2bf(fmaxf(acc[mi][ni][2] + bias, 0.f));
                o.w = f2bf(fmaxf(acc[mi][ni][3] + bias, 0.f));
                *(ushort4*)(h1t + (size_t)colf * NN + row) = o;
            }
        }
    }
}

// ---------------- atomic-free Wbt build (bf16, dense writes) ----------------

__global__ __launch_bounds__(256) void k_bw(
    const int* __restrict__ rowptr, const unsigned* __restrict__ col,
    const int* __restrict__ goff, u16* __restrict__ Wbt) {
    int b = blockIdx.x;
    int t = threadIdx.x;
    if (b < 256) {
        __shared__ float bins[BWW];
        int g = b >> 2, w = b & 3;
        int lo = w * BWW;
        for (int i = t; i < BWW; i += 256) bins[i] = 0.f;
        __syncthreads();
        int ebeg = rowptr[goff[g]], eend = rowptr[goff[g + 1]];
        for (int i = ebeg + t; i < eend; i += 256) {
            unsigned c = col[i];
            unsigned sl = (c & 0x1FFFFu) - lo;
            if (sl < (unsigned)BWW) atomicAdd(&bins[sl], 1.0f / (float)(c >> 17));
        }
        __syncthreads();
        u16* out = Wbt + (size_t)g * NN + lo;
        for (int k = t; k < BWW / 4; k += 256) {
            ushort4 o;
            o.x = f2bf(bins[4 * k + 0]); o.y = f2bf(bins[4 * k + 1]);
            o.z = f2bf(bins[4 * k + 2]); o.w = f2bf(bins[4 * k + 3]);
            *(ushort4*)(out + 4 * k) = o;
        }
    } else {
        int g = b - 256;
        int a = goff[g], bnd = goff[g + 1];
        u16* out = Wbt + (size_t)(NG + g) * NN;
        for (int k = t; k < NN / 4; k += 256) {
            int c0 = 4 * k;
            ushort4 o;
            o.x = (c0 + 0 >= a && c0 + 0 < bnd) ? 0x3F80 : 0;
            o.y = (c0 + 1 >= a && c0 + 1 < bnd) ? 0x3F80 : 0;
            o.z = (c0 + 2 >= a && c0 + 2 < bnd) ? 0x3F80 : 0;
            o.w = (c0 + 3 >= a && c0 + 3 < bnd) ? 0x3F80 : 0;
            *(ushort4*)(out + c0) = o;
        }
    }
}

// ---------------- pool GEMM (split-K MFMA): P = Wbt @ h1t^T ----------------

#define KCHUNK 1024

__global__ __launch_bounds__(256) void k_poolg(
    const u16* __restrict__ Wbt, const u16* __restrict__ h1t, float* __restrict__ P8) {
    __shared__ u16 As[128][40];
    __shared__ u16 Bs[128][40];
    int t = threadIdx.x;
    int kbase = blockIdx.x * KCHUNK;
    int n0 = blockIdx.y * 128;
    int krem = NN - kbase;
    int ksteps = (krem < KCHUNK ? krem : KCHUNK) >> 5;
    int wave = t >> 6, lane = t & 63;
    int wm = wave & 1, wn = wave >> 1;
    int lm = lane & 15, quad = lane >> 4;
    float* P = P8 + (size_t)(blockIdx.x & 7) * 128 * HID;
    f32x4 acc[4][4] = {};
    for (int ks = 0; ks < ksteps; ks++) {
        int k0 = kbase + ks * 32;
#pragma unroll
        for (int i = 0; i < 2; i++) {
            int flat = t + i * 256;
            int r = flat >> 2, q = flat & 3;
            uint4 v = *(const uint4*)(Wbt + (size_t)r * NN + k0 + q * 8);
            *(uint4*)&As[r][q * 8] = v;
            uint4 w = *(const uint4*)(h1t + (size_t)(n0 + r) * NN + k0 + q * 8);
            *(uint4*)&Bs[r][q * 8] = w;
        }
        __syncthreads();
        s16x8 af[4], bfr[4];
#pragma unroll
        for (int i = 0; i < 4; i++) {
            af[i]  = *(const s16x8*)&As[wm * 64 + i * 16 + lm][quad * 8];
            bfr[i] = *(const s16x8*)&Bs[wn * 64 + i * 16 + lm][quad * 8];
        }
#pragma unroll
        for (int mi = 0; mi < 4; mi++)
#pragma unroll
            for (int ni = 0; ni < 4; ni++)
                acc[mi][ni] = __builtin_amdgcn_mfma_f32_16x16x32_bf16(
                    af[mi], bfr[ni], acc[mi][ni], 0, 0, 0);
        __syncthreads();
    }
#pragma unroll
    for (int mi = 0; mi < 4; mi++)
#pragma unroll
        for (int ni = 0; ni < 4; ni++) {
            int gcol = wm * 64 + mi * 16 + quad * 4;
            int feat = n0 + wn * 64 + ni * 16 + lm;
#pragma unroll
            for (int r = 0; r < 4; r++)
                atomicAdd(&P[(gcol + r) * HID + feat], acc[mi][ni][r]);
        }
}

// ---------------- head ----------------

__global__ void k_head(const float* __restrict__ P8, const int* __restrict__ gcnt,
                       const float* __restrict__ gattr,
                       const float* __restrict__ W2l, const float* __restrict__ b2,
                       const float* __restrict__ W2r,
                       const float* __restrict__ Wf1, const float* __restrict__ bf1,
                       const float* __restrict__ Wf2, const float* __restrict__ bf2v,
                       float* __restrict__ out) {
    __shared__ float pa[HID], ph[HID], gv[HID + NATTR];
    __shared__ float red[256];
    int g = blockIdx.x, t = threadIdx.x;
    float sa = 0.f, sh = 0.f;
#pragma unroll
    for (int c = 0; c < 8; c++) {
        sa += P8[(size_t)c * 128 * HID + g * HID + t];
        sh += P8[(size_t)c * 128 * HID + (NG + g) * HID + t];
    }
    pa[t] = sa; ph[t] = sh;
    __syncthreads();
    float s = 0.f;
    for (int k = 0; k < HID; k++)
        s += pa[k] * W2l[k * HID + t] + ph[k] * W2r[k * HID + t];
    float invc = 1.f / (float)imaxi(gcnt[g], 1);
    gv[t] = s * invc + b2[t];
    if (t < NATTR) gv[HID + t] = gattr[g * NATTR + t];
    __syncthreads();
    float h = bf1[t];
    for (int k = 0; k < HID + NATTR; k++) h += gv[k] * Wf1[k * HID + t];
    h = fmaxf(h, 0.f);
    red[t] = h * Wf2[t];
    __syncthreads();
    for (int off = 128; off > 0; off >>= 1) {
        if (t < off) red[t] += red[t + off];
        __syncthreads();
    }
    if (t == 0) out[g] = red[0] + bf2v[0];
}

// ---------------- launch ----------------

extern "C" void kernel_launch(void* const* d_in, const int* in_sizes, int n_in,
                              void* d_out, int out_size, void* d_ws, size_t ws_size,
                              hipStream_t stream) {
    (void)in_sizes; (void)n_in; (void)out_size; (void)ws_size;
    const float* x     = (const float*)d_in[0];
    const int*   ei    = (const int*)d_in[1];
    const int*   batch = (const int*)d_in[2];
    const float* gattr = (const float*)d_in[3];
    const float* W1l   = (const float*)d_in[4];
    const float* b1    = (const float*)d_in[5];
    const float* W1r   = (const float*)d_in[6];
    const float* W2l   = (const float*)d_in[7];
    const float* b2    = (const float*)d_in[8];
    const float* W2r   = (const float*)d_in[9];
    const float* Wf1   = (const float*)d_in[10];
    const float* bf1   = (const float*)d_in[11];
    const float* Wf2   = (const float*)d_in[12];
    const float* bf2v  = (const float*)d_in[13];
    float* out = (float*)d_out;

    uint8_t* w = (uint8_t*)d_ws;
    size_t off = 0;
    auto alloc = [&](size_t bytes) -> void* {
        void* p = w + off;
        off += (bytes + 255) & ~(size_t)255;
        return p;
    };
    u16*      xb     = (u16*)alloc((size_t)NN * DIN * 2);        // 25.6 MB
    u16*      agg1   = (u16*)alloc((size_t)NN * DIN * 2);        // 25.6 MB
    u16*      h1t    = (u16*)alloc((size_t)NN * HID * 2);        // 51.2 MB
    u16*      Wbt    = (u16*)alloc((size_t)128 * NN * 2);        // 25.6 MB
    u16*      W1lt   = (u16*)alloc((size_t)HID * DIN * 2);
    u16*      W1rt   = (u16*)alloc((size_t)HID * DIN * 2);
    uint2*    pairs  = (uint2*)alloc((size_t)NBK * CAP * 8);     // 19.2 MB
    int*      rowptr = (int*)alloc((size_t)(NN + 1) * 4);
    unsigned* col    = (unsigned*)alloc((size_t)NE * 4);         // 6.4 MB
    int*      cursor = (int*)alloc((NBK + 1) * 4);
    int*      ebase  = (int*)alloc((NBK + 1) * 4);
    int*      goff   = (int*)alloc((NG + 1) * 4);
    int*      gcnt   = (int*)alloc(NG * 4);
    float*    P8     = (float*)alloc((size_t)8 * 128 * HID * 4);  // 1 MB

    k_init<<<257, 256, 0, stream>>>((float4*)P8, batch, goff, gcnt, cursor);
    k_prep<<<CB, 256, 0, stream>>>((const float4*)x, (ushort4*)xb, W1l, W1r, W1lt, W1rt);

    // CSR via radix partition (zero global-scatter atomics on data)
    k_part<<<(NE + PCH - 1) / PCH, 256, 0, stream>>>(ei, cursor, pairs);
    k_bscan<<<1, 256, 0, stream>>>(cursor, ebase);
    k_csr<<<NBK, 256, 0, stream>>>(pairs, cursor, ebase, rowptr, col);

    // layer 1
    k_agg<<<NN / 4, 256, 0, stream>>>((const uint2*)xb, (uint2*)agg1, rowptr, col);
    dim3 g1((NN + 127) / 128, HID / 128);
    k_gemm1<<<g1, 256, 0, stream>>>(agg1, xb, W1lt, W1rt, b1, h1t);

    // pooled layer-2: atomic-free Wbt build + MFMA GEMM
    k_bw<<<320, 256, 0, stream>>>(rowptr, col, goff, Wbt);
    dim3 g2((NN + KCHUNK - 1) / KCHUNK, HID / 128);
    k_poolg<<<g2, 256, 0, stream>>>(Wbt, h1t, P8);

    k_head<<<NG, 256, 0, stream>>>(P8, gcnt, gattr, W2l, b2, W2r, Wf1, bf1, Wf2, bf2v, out);
}

// Round 11
// 367.675 us; speedup vs baseline: 1.7362x; 1.0569x over previous
//
#include <hip/hip_runtime.h>
#include <stdint.h>

#define NN 100000
#define NE 1600000
#define NG 64
#define DIN 128
#define HID 256
#define NATTR 8
#define NBK 391      // dst buckets of 256 nodes
#define CAP 6144     // bucket capacity (max ~4400)
#define PCH 4096     // edges per partition chunk
#define BWW 25000    // Wbt build window
#define CB 12756     // cast/tw blocks: (NN*DIN/4 + 65536)/256

typedef unsigned short u16;
typedef __attribute__((ext_vector_type(8))) short s16x8;
typedef __attribute__((ext_vector_type(4))) float f32x4;

__device__ __forceinline__ int imaxi(int a, int b) { return a > b ? a : b; }
__device__ __forceinline__ u16 f2bf(float f) {
    unsigned u = __float_as_uint(f);
    return (u16)((u + 0x7fffu + ((u >> 16) & 1u)) >> 16);  // RNE
}
__device__ __forceinline__ void gload16(const void* g, void* l) {
    __builtin_amdgcn_global_load_lds((const __attribute__((address_space(1))) void*)g,
                                     (__attribute__((address_space(3))) void*)l, 16, 0, 0);
}

// ---------------- prep: cast x, transpose W1, zero P8/cursor, goff/gcnt ----------------

__global__ void k_prep(const float4* __restrict__ x4, ushort4* __restrict__ xb4,
                       const float* __restrict__ W1l, const float* __restrict__ W1r,
                       u16* __restrict__ W1lt, u16* __restrict__ W1rt,
                       float4* __restrict__ P84, const int* __restrict__ batch,
                       int* __restrict__ goff, int* __restrict__ gcnt,
                       int* __restrict__ cursor) {
    int b = blockIdx.x, t = threadIdx.x;
    if (b < CB) {
        int i = b * 256 + t;
        const int NX4 = NN * DIN / 4;  // 3,200,000
        if (i < NX4) {
            float4 v = x4[i];
            ushort4 o;
            o.x = f2bf(v.x); o.y = f2bf(v.y); o.z = f2bf(v.z); o.w = f2bf(v.w);
            xb4[i] = o;
        } else {
            int j = i - NX4;
            if (j < 32768) {
                int n = j >> 7, k = j & 127;
                W1lt[j] = f2bf(W1l[k * HID + n]);
            } else if (j < 65536) {
                int jj = j - 32768;
                int n = jj >> 7, k = jj & 127;
                W1rt[jj] = f2bf(W1r[k * HID + n]);
            }
        }
    } else if (b < CB + 256) {
        int i = (b - CB) * 256 + t;  // exactly 65536 = 8*128*HID/4
        P84[i] = make_float4(0.f, 0.f, 0.f, 0.f);
    } else {
        for (int i = t; i < NBK; i += 256) cursor[i] = 0;
        int g = t;
        if (g <= NG) {
            int lo = 0, hi = NN;
            while (lo < hi) {
                int mid = (lo + hi) >> 1;
                if (batch[mid] < g) lo = mid + 1; else hi = mid;
            }
            goff[g] = lo;
        }
        __syncthreads();
        if (g < NG) gcnt[g] = goff[g + 1] - goff[g];
    }
}

// ---------------- pass 1: radix partition, packed (dlocal<<24)|src ----------------

__global__ __launch_bounds__(256) void k_part(const int* __restrict__ ei,
                                              int* __restrict__ cursor,
                                              unsigned* __restrict__ pairs) {
    __shared__ unsigned spk[PCH];       // 16 KB
    __shared__ unsigned short sbk[PCH]; // 8 KB
    __shared__ int hist[NBK], gb[NBK];
    __shared__ int sc[512];
    int t = threadIdx.x;
    int c0 = blockIdx.x * PCH;
    int n = NE - c0; if (n > PCH) n = PCH;
    for (int i = t; i < NBK; i += 256) hist[i] = 0;
    __syncthreads();
    unsigned mypk[16]; unsigned short mybk[16]; int myoff[16];
#pragma unroll
    for (int j = 0; j < 16; j++) {
        int i = t + j * 256;
        myoff[j] = -1;
        if (i < n) {
            int e = c0 + i;
            unsigned d = (unsigned)__builtin_nontemporal_load(&ei[NE + e]);
            unsigned s = (unsigned)__builtin_nontemporal_load(&ei[e]);
            unsigned bk = d >> 8;
            mypk[j] = ((d & 255u) << 24) | s;
            mybk[j] = (unsigned short)bk;
            myoff[j] = atomicAdd(&hist[bk], 1);
        }
    }
    __syncthreads();
    sc[t] = (t < NBK) ? hist[t] : 0;
    sc[t + 256] = (t + 256 < NBK) ? hist[t + 256] : 0;
    __syncthreads();
    for (int off = 1; off < 512; off <<= 1) {
        int v0 = (t >= off) ? sc[t - off] : 0;
        int v1 = (t + 256 >= off) ? sc[t + 256 - off] : 0;
        __syncthreads();
        sc[t] += v0; sc[t + 256] += v1;
        __syncthreads();
    }
    if (t < NBK && hist[t] > 0) gb[t] = atomicAdd(&cursor[t], hist[t]);
    if (t + 256 < NBK && hist[t + 256] > 0)
        gb[t + 256] = atomicAdd(&cursor[t + 256], hist[t + 256]);
    __syncthreads();
#pragma unroll
    for (int j = 0; j < 16; j++) {
        if (myoff[j] >= 0) {
            int bk = mybk[j];
            int pos = sc[bk] - hist[bk] + myoff[j];
            spk[pos] = mypk[j];
            sbk[pos] = (unsigned short)bk;
        }
    }
    __syncthreads();
    for (int i = t; i < n; i += 256) {
        int bk = sbk[i];
        int local = gb[bk] + (i - (sc[bk] - hist[bk]));
        pairs[(size_t)bk * CAP + local] = spk[i];
    }
}

// ---------------- pass 2: per-bucket CSR (self-computed base, LDS only) ----------------

__global__ __launch_bounds__(256) void k_csr(const unsigned* __restrict__ pairs,
                                             const int* __restrict__ cursor,
                                             int* __restrict__ rowptr,
                                             unsigned* __restrict__ col) {
    __shared__ unsigned colL[CAP];   // 24 KB
    __shared__ int csc[512];
    __shared__ int cnt[256], cur[256], sc[256];
    int b = blockIdx.x, t = threadIdx.x;
    csc[t] = (t < NBK) ? cursor[t] : 0;
    csc[t + 256] = (t + 256 < NBK) ? cursor[t + 256] : 0;
    __syncthreads();
    for (int off = 1; off < 512; off <<= 1) {
        int v0 = (t >= off) ? csc[t - off] : 0;
        int v1 = (t + 256 >= off) ? csc[t + 256 - off] : 0;
        __syncthreads();
        csc[t] += v0; csc[t + 256] += v1;
        __syncthreads();
    }
    int obase = (b == 0) ? 0 : csc[b - 1];
    int ecnt = cursor[b];
    const unsigned* pp = pairs + (size_t)b * CAP;
    cnt[t] = 0;
    __syncthreads();
    for (int i = t; i < ecnt; i += 256)
        atomicAdd(&cnt[pp[i] >> 24], 1);
    __syncthreads();
    sc[t] = cnt[t];
    __syncthreads();
    for (int off = 1; off < 256; off <<= 1) {
        int v = (t >= off) ? sc[t - off] : 0;
        __syncthreads();
        sc[t] += v;
        __syncthreads();
    }
    int lr = sc[t] - cnt[t];
    cur[t] = lr;
    int node = (b << 8) + t;
    if (node < NN) rowptr[node] = obase + lr;
    if (b == NBK - 1 && t == 0) rowptr[NN] = obase + ecnt;
    __syncthreads();
    for (int i = t; i < ecnt; i += 256) {
        unsigned p = pp[i];
        int dl = p >> 24;
        int pos = atomicAdd(&cur[dl], 1);
        int dd = cnt[dl]; if (dd > 32767) dd = 32767;
        colL[pos] = ((unsigned)dd << 17) | (p & 0xFFFFFFu);
    }
    __syncthreads();
    for (int i = t; i < ecnt; i += 256)
        col[obase + i] = colL[i];
}

// ---------------- layer-1 mean aggregation (quarter-wave, uint4 rows) ----------------
// wave/node; 16 lanes x 16 B cover the 256 B row; 4 edges in parallel (quarters),
// main loop 16 edges = 4 outstanding dwordx4 loads per lane.

__global__ void k_agg(const uint4* __restrict__ xb4, uint4* __restrict__ agg4,
                      const int* __restrict__ rowptr, const unsigned* __restrict__ col) {
    int node = blockIdx.x * 4 + (threadIdx.x >> 6);
    int lane = threadIdx.x & 63;
    if (node >= NN) return;
    int qtr = lane >> 4, li = lane & 15;
    int s = rowptr[node], e = rowptr[node + 1];
    float a0 = 0, a1 = 0, a2 = 0, a3 = 0, a4 = 0, a5 = 0, a6 = 0, a7 = 0;
#define ACC8(V) do { \
        a0 += __uint_as_float((V).x << 16); a1 += __uint_as_float((V).x & 0xffff0000u); \
        a2 += __uint_as_float((V).y << 16); a3 += __uint_as_float((V).y & 0xffff0000u); \
        a4 += __uint_as_float((V).z << 16); a5 += __uint_as_float((V).z & 0xffff0000u); \
        a6 += __uint_as_float((V).w << 16); a7 += __uint_as_float((V).w & 0xffff0000u); } while (0)
    int i = s;
    for (; i + 16 <= e; i += 16) {
        unsigned c0 = col[i + qtr] & 0x1FFFFu;
        unsigned c1 = col[i + 4 + qtr] & 0x1FFFFu;
        unsigned c2 = col[i + 8 + qtr] & 0x1FFFFu;
        unsigned c3 = col[i + 12 + qtr] & 0x1FFFFu;
        uint4 w0 = xb4[(size_t)c0 * 16 + li];
        uint4 w1 = xb4[(size_t)c1 * 16 + li];
        uint4 w2 = xb4[(size_t)c2 * 16 + li];
        uint4 w3 = xb4[(size_t)c3 * 16 + li];
        ACC8(w0); ACC8(w1); ACC8(w2); ACC8(w3);
    }
    for (; i + 4 <= e; i += 4) {
        unsigned c = col[i + qtr] & 0x1FFFFu;
        uint4 wv = xb4[(size_t)c * 16 + li];
        ACC8(wv);
    }
    if (i + qtr < e) {
        unsigned c = col[i + qtr] & 0x1FFFFu;
        uint4 wv = xb4[(size_t)c * 16 + li];
        ACC8(wv);
    }
#undef ACC8
    a0 += __shfl_xor(a0, 16); a1 += __shfl_xor(a1, 16);
    a2 += __shfl_xor(a2, 16); a3 += __shfl_xor(a3, 16);
    a4 += __shfl_xor(a4, 16); a5 += __shfl_xor(a5, 16);
    a6 += __shfl_xor(a6, 16); a7 += __shfl_xor(a7, 16);
    a0 += __shfl_xor(a0, 32); a1 += __shfl_xor(a1, 32);
    a2 += __shfl_xor(a2, 32); a3 += __shfl_xor(a3, 32);
    a4 += __shfl_xor(a4, 32); a5 += __shfl_xor(a5, 32);
    a6 += __shfl_xor(a6, 32); a7 += __shfl_xor(a7, 32);
    if (qtr == 0) {
        float inv = 1.f / (float)imaxi(e - s, 1);
        uint4 o;
        o.x = (((unsigned)f2bf(a1 * inv)) << 16) | (unsigned)f2bf(a0 * inv);
        o.y = (((unsigned)f2bf(a3 * inv)) << 16) | (unsigned)f2bf(a2 * inv);
        o.z = (((unsigned)f2bf(a5 * inv)) << 16) | (unsigned)f2bf(a4 * inv);
        o.w = (((unsigned)f2bf(a7 * inv)) << 16) | (unsigned)f2bf(a6 * inv);
        agg4[(size_t)node * 16 + li] = o;
    }
}

// ---------------- MFMA GEMM1: h1t = relu(agg1@W1l + x@W1r + b1)^T ----------------
// 128x256 tile, 8 waves, unpadded LDS, global_load_lds width-16 staging (m97 recipe).

__global__ __launch_bounds__(512) void k_gemm1(
    const u16* __restrict__ agg1, const u16* __restrict__ xb,
    const u16* __restrict__ W1lt, const u16* __restrict__ W1rt,
    const float* __restrict__ b1, u16* __restrict__ h1t) {
    __shared__ u16 As[128][32];   // 8 KB
    __shared__ u16 Bs[256][32];   // 16 KB
    int t = threadIdx.x;
    int m0 = blockIdx.x * 128;
    int wave = t >> 6, lane = t & 63;
    int wm = wave & 1, wn = wave >> 1;
    int lm = lane & 15, quad = lane >> 4;
    int ar = t >> 2, aq = t & 3;
    f32x4 acc[4][4] = {};
    const u16* Ap = agg1;
    const u16* Bp = W1lt;
#pragma unroll
    for (int ph = 0; ph < 2; ph++) {
        for (int k0 = 0; k0 < DIN; k0 += 32) {
            gload16(Ap + (size_t)(m0 + ar) * DIN + k0 + aq * 8, &As[wave * 16][0]);
#pragma unroll
            for (int i = 0; i < 2; i++) {
                int r = (t + i * 512) >> 2;
                gload16(Bp + (size_t)r * DIN + k0 + aq * 8, &Bs[wave * 16 + i * 128][0]);
            }
            __syncthreads();
            s16x8 af[4], bfr[4];
#pragma unroll
            for (int i = 0; i < 4; i++) {
                af[i]  = *(const s16x8*)&As[wm * 64 + i * 16 + lm][quad * 8];
                bfr[i] = *(const s16x8*)&Bs[wn * 64 + i * 16 + lm][quad * 8];
            }
#pragma unroll
            for (int mi = 0; mi < 4; mi++)
#pragma unroll
                for (int ni = 0; ni < 4; ni++)
                    acc[mi][ni] = __builtin_amdgcn_mfma_f32_16x16x32_bf16(
                        af[mi], bfr[ni], acc[mi][ni], 0, 0, 0);
            __syncthreads();
        }
        Ap = xb; Bp = W1rt;
    }
#pragma unroll
    for (int ni = 0; ni < 4; ni++) {
        int colf = wn * 64 + ni * 16 + lm;  // feature 0..255
        float bias = b1[colf];
#pragma unroll
        for (int mi = 0; mi < 4; mi++) {
            int row = m0 + wm * 64 + mi * 16 + quad * 4;  // node
            if (row < NN) {
                ushort4 o;
                o.x = f2bf(fmaxf(acc[mi][ni][0] + bias, 0.f));
                o.y = f2bf(fmaxf(acc[mi][ni][1] + bias, 0.f));
                o.z = f2bf(fmaxf(acc[mi][ni][2] + bias, 0.f));
                o.w = f2bf(fmaxf(acc[mi][ni][3] + bias, 0.f));
                *(ushort4*)(h1t + (size_t)colf * NN + row) = o;
            }
        }
    }
}

// ---------------- atomic-free Wbt build (bf16, dense writes) ----------------

__global__ __launch_bounds__(256) void k_bw(
    const int* __restrict__ rowptr, const unsigned* __restrict__ col,
    const int* __restrict__ goff, u16* __restrict__ Wbt) {
    int b = blockIdx.x, t = threadIdx.x;
    if (b < 256) {
        __shared__ float bins[BWW];
        int g = b >> 2, w = b & 3;
        int lo = w * BWW;
        for (int i = t; i < BWW; i += 256) bins[i] = 0.f;
        __syncthreads();
        int ebeg = rowptr[goff[g]], eend = rowptr[goff[g + 1]];
        for (int i = ebeg + t; i < eend; i += 256) {
            unsigned c = col[i];
            unsigned sl = (c & 0x1FFFFu) - lo;
            if (sl < (unsigned)BWW) atomicAdd(&bins[sl], 1.0f / (float)(c >> 17));
        }
        __syncthreads();
        u16* out = Wbt + (size_t)g * NN + lo;
        for (int k = t; k < BWW / 4; k += 256) {
            ushort4 o;
            o.x = f2bf(bins[4 * k + 0]); o.y = f2bf(bins[4 * k + 1]);
            o.z = f2bf(bins[4 * k + 2]); o.w = f2bf(bins[4 * k + 3]);
            *(ushort4*)(out + 4 * k) = o;
        }
    } else {
        int g = b - 256;
        int a = goff[g], bnd = goff[g + 1];
        u16* out = Wbt + (size_t)(NG + g) * NN;
        for (int k = t; k < NN / 4; k += 256) {
            int c0 = 4 * k;
            ushort4 o;
            o.x = (c0 + 0 >= a && c0 + 0 < bnd) ? 0x3F80 : 0;
            o.y = (c0 + 1 >= a && c0 + 1 < bnd) ? 0x3F80 : 0;
            o.z = (c0 + 2 >= a && c0 + 2 < bnd) ? 0x3F80 : 0;
            o.w = (c0 + 3 >= a && c0 + 3 < bnd) ? 0x3F80 : 0;
            *(ushort4*)(out + c0) = o;
        }
    }
}

// ---------------- pool GEMM: P = Wbt @ h1t^T (128x256, split-K 512) ----------------

#define KCHUNK 512

__global__ __launch_bounds__(512) void k_poolg(
    const u16* __restrict__ Wbt, const u16* __restrict__ h1t, float* __restrict__ P8) {
    __shared__ u16 As[128][32];
    __shared__ u16 Bs[256][32];
    int t = threadIdx.x;
    int kbase = blockIdx.x * KCHUNK;
    int krem = NN - kbase;
    int ksteps = (krem < KCHUNK ? krem : KCHUNK) >> 5;
    int wave = t >> 6, lane = t & 63;
    int wm = wave & 1, wn = wave >> 1;
    int lm = lane & 15, quad = lane >> 4;
    int ar = t >> 2, aq = t & 3;
    float* P = P8 + (size_t)(blockIdx.x & 7) * 128 * HID;
    f32x4 acc[4][4] = {};
    for (int ks = 0; ks < ksteps; ks++) {
        int k0 = kbase + ks * 32;
        gload16(Wbt + (size_t)ar * NN + k0 + aq * 8, &As[wave * 16][0]);
#pragma unroll
        for (int i = 0; i < 2; i++) {
            int r = (t + i * 512) >> 2;
            gload16(h1t + (size_t)r * NN + k0 + aq * 8, &Bs[wave * 16 + i * 128][0]);
        }
        __syncthreads();
        s16x8 af[4], bfr[4];
#pragma unroll
        for (int i = 0; i < 4; i++) {
            af[i]  = *(const s16x8*)&As[wm * 64 + i * 16 + lm][quad * 8];
            bfr[i] = *(const s16x8*)&Bs[wn * 64 + i * 16 + lm][quad * 8];
        }
#pragma unroll
        for (int mi = 0; mi < 4; mi++)
#pragma unroll
            for (int ni = 0; ni < 4; ni++)
                acc[mi][ni] = __builtin_amdgcn_mfma_f32_16x16x32_bf16(
                    af[mi], bfr[ni], acc[mi][ni], 0, 0, 0);
        __syncthreads();
    }
#pragma unroll
    for (int mi = 0; mi < 4; mi++)
#pragma unroll
        for (int ni = 0; ni < 4; ni++) {
            int gcol = wm * 64 + mi * 16 + quad * 4;
            int feat = wn * 64 + ni * 16 + lm;
#pragma unroll
            for (int r = 0; r < 4; r++)
                atomicAdd(&P[(gcol + r) * HID + feat], acc[mi][ni][r]);
        }
}

// ---------------- head ----------------

__global__ void k_head(const float* __restrict__ P8, const int* __restrict__ gcnt,
                       const float* __restrict__ gattr,
                       const float* __restrict__ W2l, const float* __restrict__ b2,
                       const float* __restrict__ W2r,
                       const float* __restrict__ Wf1, const float* __restrict__ bf1,
                       const float* __restrict__ Wf2, const float* __restrict__ bf2v,
                       float* __restrict__ out) {
    __shared__ float pa[HID], ph[HID], gv[HID + NATTR];
    __shared__ float red[256];
    int g = blockIdx.x, t = threadIdx.x;
    float sa = 0.f, sh = 0.f;
#pragma unroll
    for (int c = 0; c < 8; c++) {
        sa += P8[(size_t)c * 128 * HID + g * HID + t];
        sh += P8[(size_t)c * 128 * HID + (NG + g) * HID + t];
    }
    pa[t] = sa; ph[t] = sh;
    __syncthreads();
    float s = 0.f;
    for (int k = 0; k < HID; k++)
        s += pa[k] * W2l[k * HID + t] + ph[k] * W2r[k * HID + t];
    float invc = 1.f / (float)imaxi(gcnt[g], 1);
    gv[t] = s * invc + b2[t];
    if (t < NATTR) gv[HID + t] = gattr[g * NATTR + t];
    __syncthreads();
    float h = bf1[t];
    for (int k = 0; k < HID + NATTR; k++) h += gv[k] * Wf1[k * HID + t];
    h = fmaxf(h, 0.f);
    red[t] = h * Wf2[t];
    __syncthreads();
    for (int off = 128; off > 0; off >>= 1) {
        if (t < off) red[t] += red[t + off];
        __syncthreads();
    }
    if (t == 0) out[g] = red[0] + bf2v[0];
}

// ---------------- launch ----------------

extern "C" void kernel_launch(void* const* d_in, const int* in_sizes, int n_in,
                              void* d_out, int out_size, void* d_ws, size_t ws_size,
                              hipStream_t stream) {
    (void)in_sizes; (void)n_in; (void)out_size; (void)ws_size;
    const float* x     = (const float*)d_in[0];
    const int*   ei    = (const int*)d_in[1];
    const int*   batch = (const int*)d_in[2];
    const float* gattr = (const float*)d_in[3];
    const float* W1l   = (const float*)d_in[4];
    const float* b1    = (const float*)d_in[5];
    const float* W1r   = (const float*)d_in[6];
    const float* W2l   = (const float*)d_in[7];
    const float* b2    = (const float*)d_in[8];
    const float* W2r   = (const float*)d_in[9];
    const float* Wf1   = (const float*)d_in[10];
    const float* bf1   = (const float*)d_in[11];
    const float* Wf2   = (const float*)d_in[12];
    const float* bf2v  = (const float*)d_in[13];
    float* out = (float*)d_out;

    uint8_t* w = (uint8_t*)d_ws;
    size_t off = 0;
    auto alloc = [&](size_t bytes) -> void* {
        void* p = w + off;
        off += (bytes + 255) & ~(size_t)255;
        return p;
    };
    u16*      xb     = (u16*)alloc((size_t)NN * DIN * 2);        // 25.6 MB
    u16*      agg1   = (u16*)alloc((size_t)NN * DIN * 2);        // 25.6 MB
    u16*      h1t    = (u16*)alloc((size_t)NN * HID * 2);        // 51.2 MB
    u16*      Wbt    = (u16*)alloc((size_t)128 * NN * 2);        // 25.6 MB
    u16*      W1lt   = (u16*)alloc((size_t)HID * DIN * 2);
    u16*      W1rt   = (u16*)alloc((size_t)HID * DIN * 2);
    unsigned* pairs  = (unsigned*)alloc((size_t)NBK * CAP * 4);  // 9.6 MB
    int*      rowptr = (int*)alloc((size_t)(NN + 1) * 4);
    unsigned* col    = (unsigned*)alloc((size_t)NE * 4);         // 6.4 MB
    int*      cursor = (int*)alloc((NBK + 1) * 4);
    int*      goff   = (int*)alloc((NG + 1) * 4);
    int*      gcnt   = (int*)alloc(NG * 4);
    float*    P8     = (float*)alloc((size_t)8 * 128 * HID * 4); // 1 MB

    k_prep<<<CB + 257, 256, 0, stream>>>((const float4*)x, (ushort4*)xb, W1l, W1r,
                                         W1lt, W1rt, (float4*)P8, batch, goff, gcnt,
                                         cursor);

    k_part<<<(NE + PCH - 1) / PCH, 256, 0, stream>>>(ei, cursor, pairs);
    k_csr<<<NBK, 256, 0, stream>>>(pairs, cursor, rowptr, col);

    k_agg<<<NN / 4, 256, 0, stream>>>((const uint4*)xb, (uint4*)agg1, rowptr, col);
    k_gemm1<<<(NN + 127) / 128, 512, 0, stream>>>(agg1, xb, W1lt, W1rt, b1, h1t);

    k_bw<<<320, 256, 0, stream>>>(rowptr, col, goff, Wbt);
    k_poolg<<<(NN + KCHUNK - 1) / KCHUNK, 512, 0, stream>>>(Wbt, h1t, P8);

    k_head<<<NG, 256, 0, stream>>>(P8, gcnt, gattr, W2l, b2, W2r, Wf1, bf1, Wf2, bf2v, out);
}